// Round 11
// baseline (251.875 us; speedup 1.0000x reference)
//
#include <hip/hip_runtime.h>
#include <cfloat>

typedef float f32x4 __attribute__((ext_vector_type(4)));
typedef _Float16 h8 __attribute__((ext_vector_type(8)));

static __device__ __forceinline__ unsigned umin_(unsigned a, unsigned b) { return a < b ? a : b; }
static __device__ __forceinline__ unsigned umax_(unsigned a, unsigned b) { return a > b ? a : b; }
// second-min update: med3(b1, b2, k) == min(b2, max(k, b1)) given b1 <= b2
static __device__ __forceinline__ unsigned med3_(unsigned a, unsigned b, unsigned c) {
    unsigned d;
    asm("v_med3_u32 %0, %1, %2, %3" : "=v"(d) : "v"(a), "v"(b), "v"(c));
    return d;
}

// ===========================================================================
// Activation layout: zero-padded parity-split planes, NHWC fp16 hi/lo.
// ===========================================================================

__global__ __launch_bounds__(256)
void zero_b_k(_Float16* p0, _Float16* p1, _Float16* p2, _Float16* p3,
              _Float16* p4, _Float16* p5) {
    const int s = blockIdx.y;
    _Float16* p; int np, P;
    switch (s) {
        case 0: p = p0; np = 16; P = 66; break;
        case 1: p = p1; np = 16; P = 66; break;
        case 2: p = p2; np = 16; P = 34; break;
        case 3: p = p3; np = 16; P = 34; break;
        case 4: p = p4; np = 4;  P = 34; break;
        default: p = p5; np = 4; P = 34; break;
    }
    const int plane = blockIdx.x;
    if (plane >= np) return;
    _Float16* pl = p + (size_t)plane * P * P * 128;
    const int rowN = P * 128;
    for (int i = threadIdx.x; i < rowN; i += 256) {
        pl[i] = (_Float16)0.f;
        pl[(size_t)(P - 1) * rowN + i] = (_Float16)0.f;
        const int r = i >> 7, c = i & 127;
        pl[(size_t)r * rowN + c] = (_Float16)0.f;
        pl[(size_t)r * rowN + (P - 1) * 128 + c] = (_Float16)0.f;
    }
}

// --- conv1: fp32 direct (IC=3), writes split planes ------------------------
__global__ __launch_bounds__(256)
void conv1_k(const float* __restrict__ in, const float* __restrict__ w,
             const float* __restrict__ bias,
             _Float16* __restrict__ Dh, _Float16* __restrict__ Dl) {
    __shared__ float tile[3][34 * 36];
    const int tid = threadIdx.x;
    const int tx = tid & 15, ty = tid >> 4;
    const int bx = blockIdx.x & 7, by = blockIdx.x >> 3;
    const int oc0 = blockIdx.y * 8;
    const int b = blockIdx.z;
    const int ox = bx * 16 + tx, oy = by * 16 + ty;
    const int ix0 = bx * 32 - 1, iy0 = by * 32 - 1;

    for (int f = tid; f < 3 * 34 * 34; f += 256) {
        const int ic = f / 1156, r2 = f % 1156;
        const int r = r2 / 34, c = r2 % 34;
        const int iy = iy0 + r, ix = ix0 + c;
        float v = ((unsigned)iy < 256u && (unsigned)ix < 256u)
                      ? in[((size_t)(b * 3 + ic) * 256 + iy) * 256 + ix] : 0.f;
        tile[ic][r * 36 + c] = v;
    }
    __syncthreads();

    float acc[8];
#pragma unroll
    for (int j = 0; j < 8; ++j) acc[j] = 0.f;
#pragma unroll
    for (int ic = 0; ic < 3; ++ic) {
#pragma unroll
        for (int kh = 0; kh < 4; ++kh) {
            const float2* p = (const float2*)&tile[ic][(2 * ty + kh) * 36 + 2 * tx];
            const float2 r0 = p[0], r1 = p[1];
            const float tap[4] = {r0.x, r0.y, r1.x, r1.y};
#pragma unroll
            for (int kw = 0; kw < 4; ++kw)
#pragma unroll
                for (int j = 0; j < 8; ++j)
                    acc[j] = fmaf(tap[kw], w[((oc0 + j) * 3 + ic) * 16 + kh * 4 + kw], acc[j]);
        }
    }

    h8 hv, lv;
#pragma unroll
    for (int j = 0; j < 8; ++j) {
        float r = fmaxf(acc[j] + bias[oc0 + j], 0.f);
        _Float16 h = (_Float16)r;
        hv[j] = h;
        lv[j] = (_Float16)((r - (float)h) * 2048.f);
    }
    const size_t di = (((size_t)((b * 2 + (oy & 1)) * 2 + (ox & 1)) * 66 + 1 + (oy >> 1)) * 66
                       + 1 + (ox >> 1)) * 128 + oc0;
    *(h8*)(Dh + di) = hv;
    *(h8*)(Dl + di) = lv;
}

// --- pack all three conv weights into fragment-ordered fp16 hi/lo ----------
// Bidx = ((t*4+ks)*NT + nt)*64 + lane ; lane: oc = nt*16+(l&15), ic = ks*32+(l>>4)*8+j
__global__ __launch_bounds__(256)
void pack3_k(const float* __restrict__ w2, const float* __restrict__ w3,
             const float* __restrict__ w4,
             h8* __restrict__ B2h, h8* __restrict__ B2l,
             h8* __restrict__ B3h, h8* __restrict__ B3l,
             h8* __restrict__ B4h, h8* __restrict__ B4l) {
    const float* w; h8 *Bh, *Bl; int T, NT, KHKW;
    switch (blockIdx.y) {
        case 0:  w = w2; Bh = B2h; Bl = B2l; T = 16; NT = 8; KHKW = 16; break;
        case 1:  w = w3; Bh = B3h; Bl = B3l; T = 16; NT = 8; KHKW = 16; break;
        default: w = w4; Bh = B4h; Bl = B4l; T = 9;  NT = 2; KHKW = 9;  break;
    }
    const int idx = blockIdx.x * 256 + threadIdx.x;
    if (idx >= T * 4 * NT * 64) return;
    const int lane = idx & 63;
    int r = idx >> 6;
    const int nt = r % NT; r /= NT;
    const int ks = r & 3;  r >>= 2;
    const int t = r;
    const int oc = nt * 16 + (lane & 15);
    const int icb = ks * 32 + (lane >> 4) * 8;
    h8 hv, lv;
#pragma unroll
    for (int j = 0; j < 8; ++j) {
        const float v = w[(size_t)(oc * 128 + icb + j) * KHKW + t];
        _Float16 h = (_Float16)v;
        hv[j] = h;
        lv[j] = (_Float16)((v - (float)h) * 2048.f);
    }
    Bh[idx] = hv;
    Bl[idx] = lv;
}

// --- stride-2 tap-GEMM, reg-staged T14 pipeline (conv2, conv3) -------------
// Single 64 KB tap slab (2 blocks/CU). Per tap:
//   A-loads(t) [issued first -> pre-MFMA vmcnt leaves staging in flight]
//   reg-loads of tap t+1 weights (plain global loads -> registers)
//   compute from slab
//   barrier   (only ds reads drain; staging loads still in flight)
//   ds_write tap t+1 into slab (compiler waits vmcnt here, AFTER compute)
//   barrier   (writes visible)
// HBM/L2 latency of the weight stage hides under the 12*WN MFMAs.
template<int WN, bool SPLIT>
__global__ __launch_bounds__(256)
void gemmP_k(const _Float16* __restrict__ Ah, const _Float16* __restrict__ Al,
             const h8* __restrict__ Bh, const h8* __restrict__ Bl,
             const float* __restrict__ bias,
             _Float16* __restrict__ Dh, _Float16* __restrict__ Dl,
             int OW, int OH, int PP, int dPP) {
    constexpr int NW_N = 8 / WN;     // waves along N
    constexpr int NW_M = 4 / NW_N;   // m-waves per block
    __shared__ h8 lH[2048];          // 32 KB: tap slab hi
    __shared__ h8 lL[2048];          // 32 KB: tap slab lo

    const int tid = threadIdx.x, wid = tid >> 6, l = tid & 63;
    const int nq = wid % NW_N, mi = wid / NW_N;
    const int mt = blockIdx.x * NW_M + mi;
    const int mpr = OW >> 4, mpi = OH * mpr;
    const int b = mt / mpi;
    const int rem = mt % mpi;
    const int oy = rem / mpr, ox = (rem % mpr) << 4;
    const int laneA = (l & 15) * 128 + (l >> 4) * 8;

    f32x4 a1[WN], am[WN];
#pragma unroll
    for (int s = 0; s < WN; ++s) {
        a1[s] = (f32x4){0.f, 0.f, 0.f, 0.f};
        am[s] = (f32x4){0.f, 0.f, 0.f, 0.f};
    }

    // prologue: load tap 0 into regs, write to slab
    h8 rh[8], rl[8];
#pragma unroll
    for (int i = 0; i < 8; ++i) {
        rh[i] = Bh[i * 256 + tid];
        rl[i] = Bl[i * 256 + tid];
    }
#pragma unroll
    for (int i = 0; i < 8; ++i) {
        lH[i * 256 + tid] = rh[i];
        lL[i * 256 + tid] = rl[i];
    }
    __syncthreads();

#pragma unroll 1
    for (int t = 0; t < 16; ++t) {
        // A fragments for tap t — issued FIRST (older in vmcnt order)
        const int kh = t >> 2, kw = t & 3;
        const int dy = (kh - 1) >> 1, dx = (kw - 1) >> 1;
        const int py = (kh - 1) & 1, px = (kw - 1) & 1;
        const int pidx = (b * 2 + py) * 2 + px;
        const size_t abase = ((size_t)(pidx * PP + (oy + dy + 1)) * PP
                              + (ox + dx + 1)) * 128 + laneA;
        h8 avh[4], avl[4];
#pragma unroll
        for (int ks = 0; ks < 4; ++ks) {
            avh[ks] = *(const h8*)(Ah + abase + ks * 32);
            avl[ks] = *(const h8*)(Al + abase + ks * 32);
        }
        // stage tap t+1 weights into registers (in flight under compute)
        if (t + 1 < 16) {
            const h8* sh = Bh + (size_t)(t + 1) * 2048;
            const h8* sl = Bl + (size_t)(t + 1) * 2048;
#pragma unroll
            for (int i = 0; i < 8; ++i) {
                rh[i] = sh[i * 256 + tid];
                rl[i] = sl[i * 256 + tid];
            }
        }
        // compute on the slab (ready since previous barrier)
#pragma unroll
        for (int ks = 0; ks < 4; ++ks) {
#pragma unroll
            for (int s = 0; s < WN; ++s) {
                const h8 bvh = lH[(ks * 8 + nq * WN + s) * 64 + l];
                const h8 bvl = lL[(ks * 8 + nq * WN + s) * 64 + l];
                a1[s] = __builtin_amdgcn_mfma_f32_16x16x32_f16(avh[ks], bvh, a1[s], 0, 0, 0);
                am[s] = __builtin_amdgcn_mfma_f32_16x16x32_f16(avh[ks], bvl, am[s], 0, 0, 0);
                am[s] = __builtin_amdgcn_mfma_f32_16x16x32_f16(avl[ks], bvh, am[s], 0, 0, 0);
            }
        }
        __syncthreads();   // all reads of tap t done; slab free for overwrite
        if (t + 1 < 16) {
#pragma unroll
            for (int i = 0; i < 8; ++i) {
                lH[i * 256 + tid] = rh[i];   // vmcnt wait lands here, post-compute
                lL[i * 256 + tid] = rl[i];
            }
            __syncthreads();   // writes visible for tap t+1 compute
        }
    }

    // fused finalize: bias + relu + hi/lo split
#pragma unroll
    for (int s = 0; s < WN; ++s) {
        const int oc = (nq * WN + s) * 16 + (l & 15);
        const float bv = bias[oc];
#pragma unroll
        for (int i = 0; i < 4; ++i) {
            const int row = (l >> 4) * 4 + i;
            float v = fmaf(am[s][i], 4.8828125e-4f, a1[s][i]);
            v = fmaxf(v + bv, 0.f);
            _Float16 h = (_Float16)v;
            _Float16 lo = (_Float16)((v - (float)h) * 2048.f);
            const int oxp = ox + row;
            size_t di;
            if constexpr (SPLIT) {
                di = (((size_t)((b * 2 + (oy & 1)) * 2 + (oxp & 1)) * dPP
                       + 1 + (oy >> 1)) * dPP + 1 + (oxp >> 1)) * 128 + oc;
            } else {
                di = ((size_t)(b * dPP + 1 + oy) * dPP + 1 + oxp) * 128 + oc;
            }
            Dh[di] = h;
            Dl[di] = lo;
        }
    }
}

// --- universal tap-GEMM conv (3-term fp16-split MFMA) — kept for conv4 -----
template<int S, bool FIN, int WPN, int MT>
__global__ __launch_bounds__(256)
void gemm_k(const _Float16* __restrict__ Ah, const _Float16* __restrict__ Al,
            const h8* __restrict__ Bh, const h8* __restrict__ Bl,
            float* __restrict__ part, const float* __restrict__ bias,
            _Float16* __restrict__ Dh, _Float16* __restrict__ Dl,
            int OW, int OH, int PP, int NT, int TPS, int M, int N, int dPP) {
    const int tid = threadIdx.x, wid = tid >> 6, l = tid & 63;
    const int ntb = wid % WPN;
    const int mt0 = (blockIdx.x * (4 / WPN) + wid / WPN) * MT;
    const int sp = blockIdx.y;
    const int mpr = OW >> 4, mpi = OH * mpr;
    const int laneA = (l & 15) * 128 + (l >> 4) * 8;

    int bmt[MT], oymt[MT], oxmt[MT];
#pragma unroll
    for (int m = 0; m < MT; ++m) {
        const int mt = mt0 + m;
        bmt[m] = mt / mpi;
        const int rem = mt % mpi;
        oymt[m] = rem / mpr;
        oxmt[m] = (rem % mpr) << 4;
    }

    f32x4 a1[MT][2], am[MT][2];
#pragma unroll
    for (int m = 0; m < MT; ++m)
#pragma unroll
        for (int s = 0; s < 2; ++s) {
            a1[m][s] = (f32x4){0.f, 0.f, 0.f, 0.f};
            am[m][s] = (f32x4){0.f, 0.f, 0.f, 0.f};
        }

    const int t0 = sp * TPS, t1 = t0 + TPS;
#pragma unroll 2
    for (int t = t0; t < t1; ++t) {
        int dy, dx, pidx[MT];
        if constexpr (S == 2) {
            const int kh = t >> 2, kw = t & 3;
            dy = (kh - 1) >> 1; dx = (kw - 1) >> 1;
            const int py = (kh - 1) & 1, px = (kw - 1) & 1;
#pragma unroll
            for (int m = 0; m < MT; ++m) pidx[m] = (bmt[m] * 2 + py) * 2 + px;
        } else {
            dy = t / 3 - 1; dx = t % 3 - 1;
#pragma unroll
            for (int m = 0; m < MT; ++m) pidx[m] = bmt[m];
        }
        const _Float16* pAh[MT]; const _Float16* pAl[MT];
#pragma unroll
        for (int m = 0; m < MT; ++m) {
            const size_t base = ((size_t)(pidx[m] * PP + (oymt[m] + dy + 1)) * PP
                                 + (oxmt[m] + dx + 1)) * 128 + laneA;
            pAh[m] = Ah + base;
            pAl[m] = Al + base;
        }
        const size_t bbase = ((size_t)(t * 4) * NT + ntb * 2) * 64 + l;
#pragma unroll
        for (int ks = 0; ks < 4; ++ks) {
            h8 avh[MT], avl[MT];
#pragma unroll
            for (int m = 0; m < MT; ++m) {
                avh[m] = *(const h8*)(pAh[m] + ks * 32);
                avl[m] = *(const h8*)(pAl[m] + ks * 32);
            }
#pragma unroll
            for (int s = 0; s < 2; ++s) {
                const h8 bvh = Bh[bbase + (size_t)ks * NT * 64 + s * 64];
                const h8 bvl = Bl[bbase + (size_t)ks * NT * 64 + s * 64];
#pragma unroll
                for (int m = 0; m < MT; ++m) {
                    a1[m][s] = __builtin_amdgcn_mfma_f32_16x16x32_f16(avh[m], bvh, a1[m][s], 0, 0, 0);
                    am[m][s] = __builtin_amdgcn_mfma_f32_16x16x32_f16(avh[m], bvl, am[m][s], 0, 0, 0);
                    am[m][s] = __builtin_amdgcn_mfma_f32_16x16x32_f16(avl[m], bvh, am[m][s], 0, 0, 0);
                }
            }
        }
    }

#pragma unroll
    for (int m = 0; m < MT; ++m) {
        const int mt = mt0 + m;
#pragma unroll
        for (int s = 0; s < 2; ++s) {
            const int oc = ntb * 32 + s * 16 + (l & 15);
#pragma unroll
            for (int i = 0; i < 4; ++i) {
                const int row = (l >> 4) * 4 + i;
                float v = fmaf(am[m][s][i], 4.8828125e-4f, a1[m][s][i]);
                if (!FIN) {
                    part[((size_t)sp * M + mt * 16 + row) * N + oc] = v;
                } else {
                    v = fmaxf(v + bias[oc], 0.f);
                    _Float16 h = (_Float16)v;
                    _Float16 lo = (_Float16)((v - (float)h) * 2048.f);
                    const int ox = oxmt[m] + row;
                    const int oy = oymt[m], b = bmt[m];
                    const size_t di = (((size_t)((b * 2 + (oy & 1)) * 2 + (ox & 1)) * dPP
                                        + 1 + (oy >> 1)) * dPP + 1 + (ox >> 1)) * 128 + oc;
                    Dh[di] = h;
                    Dl[di] = lo;
                }
            }
        }
    }
}

// --- conv4 finalize + fused z-split: 3 partials + bias -> zz fp32 + frags --
// zh = fp16 hi of (-2z); zl = UNSCALED fp16 lo (vq uses scaled-hi codebook).
__global__ __launch_bounds__(256)
void fin4_k(const float* __restrict__ part, const float* __restrict__ bias,
            float* __restrict__ zz, h8* __restrict__ zh, h8* __restrict__ zl) {
    const int t = blockIdx.x * 256 + threadIdx.x;
    const int m = t >> 2, g8 = (t & 3) * 8;
    float v[8];
#pragma unroll
    for (int j = 0; j < 8; ++j) v[j] = bias[g8 + j];
#pragma unroll
    for (int sp = 0; sp < 3; ++sp) {
        const float4* p = (const float4*)(part + ((size_t)sp * 4096 + m) * 32 + g8);
        float4 x0 = p[0], x1 = p[1];
        v[0] += x0.x; v[1] += x0.y; v[2] += x0.z; v[3] += x0.w;
        v[4] += x1.x; v[5] += x1.y; v[6] += x1.z; v[7] += x1.w;
    }
    float4* dst = (float4*)(zz + (size_t)m * 32 + g8);
    dst[0] = make_float4(v[0], v[1], v[2], v[3]);
    dst[1] = make_float4(v[4], v[5], v[6], v[7]);
    // fused split_z: A-fragment order, value = -2z, hi + UNSCALED lo
    h8 hv, lv;
#pragma unroll
    for (int j = 0; j < 8; ++j) {
        const float mv = -2.f * v[j];
        _Float16 h = (_Float16)mv;
        hv[j] = h;
        lv[j] = (_Float16)(mv - (float)h);
    }
    const int idx = (m >> 4) * 64 + (m & 15) + (t & 3) * 16;
    zh[idx] = hv;
    zl[idx] = lv;
}

// ===========================================================================
// VQ: fp16-split MFMA coarse argmin + certified-margin fp32 guard rescan.
// Scaled-fold scheme: codebook-hi stored as eh*2048, z-lo stored unscaled.
// acc = (nrm+512)*2048 + zh*(eh*2048) + zh*(el*2048) + zl_u*(eh*2048)
//     = 2048 * d0  -> min-tracking directly on acc bits (monotone).
// Coarse pass kept at best-measured config (R3/R8): QT=4, 128-code chunks.
// ===========================================================================
#define VQ_NSPLIT 64
#define VQ_KSPC   1024
#define VQ_NCHUNK 8             /* 128 codes per chunk */
#define VQ_TAU_S  102.4f        /* 0.05 * 2048 */
#define VQ_ABS_S  524288.0f     /* 256  * 2048 */
#define VQ_QT     4

__global__ __launch_bounds__(256)
void split_cb_k(const float* __restrict__ cb, h8* __restrict__ cbh, h8* __restrict__ cbl,
                float* __restrict__ cbn2, float* __restrict__ cbn_raw,
                unsigned* __restrict__ counter) {
    const int c = blockIdx.x * 256 + threadIdx.x;
    const float4* p = (const float4*)(cb + (size_t)c * 32);
    float e[32];
    float s = 0.f;
#pragma unroll
    for (int i = 0; i < 8; ++i) {
        float4 v = p[i];
        e[i*4+0] = v.x; e[i*4+1] = v.y; e[i*4+2] = v.z; e[i*4+3] = v.w;
        s += v.x*v.x + v.y*v.y + v.z*v.z + v.w*v.w;
    }
    cbn_raw[c] = s;
    cbn2[c]    = (s + 512.0f) * 2048.0f;   // pre-scaled accumulator init
    const int base = (c >> 4) * 64 + (c & 15);
#pragma unroll
    for (int g = 0; g < 4; ++g) {
        h8 hv, lv;
#pragma unroll
        for (int j = 0; j < 8; ++j) {
            float v = e[g*8 + j];
            _Float16 h = (_Float16)v;
            hv[j] = (_Float16)((float)h * 2048.0f);   // scaled hi (exact pow2)
            lv[j] = (_Float16)((v - (float)h) * 2048.0f);
        }
        cbh[base + g*16] = hv;
        cbl[base + g*16] = lv;
    }
    if (c == 0) *counter = 0u;
}

// --- coarse MFMA pass: VQ_QT q-tiles per wave, single scaled accumulator ---
__global__ __launch_bounds__(256, 4)
void vq_mfma_k(const h8* __restrict__ zh, const h8* __restrict__ zl,
               const uint4* __restrict__ cbh, const uint4* __restrict__ cbl,
               const float* __restrict__ cbn2,
               unsigned* __restrict__ pb1, unsigned* __restrict__ pb2,
               unsigned* __restrict__ pcol) {
    __shared__ uint4 lH[2][512];
    __shared__ uint4 lL[2][512];
    __shared__ float lN[2][128];

    const int tid = threadIdx.x;
    const int w = tid >> 6, ln = tid & 63;
    const int split = blockIdx.y;
    const int qt0 = (blockIdx.x * 4 + w) * VQ_QT;   // first q-tile of this wave

    h8 azh[VQ_QT], azl[VQ_QT];
#pragma unroll
    for (int qq = 0; qq < VQ_QT; ++qq) {
        azh[qq] = zh[(qt0 + qq) * 64 + ln];
        azl[qq] = zl[(qt0 + qq) * 64 + ln];
    }

    unsigned b1[VQ_QT][4], b2[VQ_QT][4];
#pragma unroll
    for (int qq = 0; qq < VQ_QT; ++qq)
#pragma unroll
        for (int i = 0; i < 4; ++i) { b1[qq][i] = 0x7F800000u; b2[qq][i] = 0x7F800000u; }

    const int fbase = split * (VQ_KSPC * 4);
    const int nbase = split * VQ_KSPC;

    // prologue: stage chunk 0
    {
        uint4 h0 = cbh[fbase + tid], h1 = cbh[fbase + 256 + tid];
        uint4 l0 = cbl[fbase + tid], l1 = cbl[fbase + 256 + tid];
        lH[0][tid] = h0; lH[0][tid + 256] = h1;
        lL[0][tid] = l0; lL[0][tid + 256] = l1;
        if (tid < 128) lN[0][tid] = cbn2[nbase + tid];
    }
    __syncthreads();

    for (int ci = 0; ci < VQ_NCHUNK; ++ci) {
        const int cur = ci & 1;
        const bool more = (ci + 1 < VQ_NCHUNK);
        uint4 nh0, nh1, nl0, nl1; float nn = 0.f;
        if (more) {
            const int nb = fbase + (ci + 1) * 512;
            nh0 = cbh[nb + tid]; nh1 = cbh[nb + 256 + tid];
            nl0 = cbl[nb + tid]; nl1 = cbl[nb + 256 + tid];
            if (tid < 128) nn = cbn2[nbase + (ci + 1) * 128 + tid];
        }

        const unsigned tcb = (unsigned)(ci * 8);
#pragma unroll
        for (int t = 0; t < 8; ++t) {
            const h8 bh = *reinterpret_cast<const h8*>(&lH[cur][t*64 + ln]);
            const h8 bl = *reinterpret_cast<const h8*>(&lL[cur][t*64 + ln]);
            const float nv = lN[cur][t*16 + (ln & 15)];   // (nrm+512)*2048
            f32x4 nvv = {nv, nv, nv, nv};                 // shared C-operand
            const unsigned tc = tcb + t;
#pragma unroll
            for (int qq = 0; qq < VQ_QT; ++qq) {
                f32x4 acc;
                acc = __builtin_amdgcn_mfma_f32_16x16x32_f16(azh[qq], bh, nvv, 0, 0, 0);
                acc = __builtin_amdgcn_mfma_f32_16x16x32_f16(azh[qq], bl, acc, 0, 0, 0);
                acc = __builtin_amdgcn_mfma_f32_16x16x32_f16(azl[qq], bh, acc, 0, 0, 0);
#pragma unroll
                for (int i = 0; i < 4; ++i) {
                    const unsigned k0 = (__float_as_uint(acc[i]) & 0xFFFFFF00u) | tc;
                    b2[qq][i] = med3_(b1[qq][i], b2[qq][i], k0);   // second-min
                    b1[qq][i] = umin_(b1[qq][i], k0);
                }
            }
        }

        if (more) {
            const int nxt = cur ^ 1;
            lH[nxt][tid] = nh0; lH[nxt][tid + 256] = nh1;
            lL[nxt][tid] = nl0; lL[nxt][tid + 256] = nl1;
            if (tid < 128) lN[nxt][tid] = nn;
        }
        __syncthreads();   // writes to nxt visible; all reads of cur complete
    }

    // reduce over the 16 code-columns (lane bits 0..3); ties -> min idx
#pragma unroll
    for (int qq = 0; qq < VQ_QT; ++qq) {
#pragma unroll
        for (int i = 0; i < 4; ++i) {
            unsigned v1 = b1[qq][i], v2 = b2[qq][i], cv = (unsigned)(ln & 15);
#pragma unroll
            for (int m = 1; m < 16; m <<= 1) {
                unsigned o1 = __shfl_xor(v1, m, 64);
                unsigned o2 = __shfl_xor(v2, m, 64);
                unsigned oc = __shfl_xor(cv, m, 64);
                unsigned nb2 = umin_(umin_(v2, o2), umax_(v1, o1));
                if (o1 < v1) cv = oc;
                v1 = umin_(v1, o1); v2 = nb2;
            }
            if ((ln & 15) == 0) {
                const int q = (qt0 + qq) * 16 + (ln >> 4) * 4 + i;
                pb1[(size_t)q * VQ_NSPLIT + split] = v1;
                pb2[(size_t)q * VQ_NSPLIT + split] = v2;
                pcol[(size_t)q * VQ_NSPLIT + split] = cv;
            }
        }
    }
}

__global__ __launch_bounds__(256)
void combine_k(const unsigned* __restrict__ pb1, const unsigned* __restrict__ pb2,
               const unsigned* __restrict__ pcol,
               unsigned* __restrict__ coarse, unsigned* __restrict__ flags,
               unsigned* __restrict__ list, unsigned* __restrict__ counter) {
    const int q = blockIdx.x * 256 + threadIdx.x;
    unsigned B1 = 0x7F800000u, B2 = 0x7F800000u, PAY = 0u;
#pragma unroll 4
    for (int s = 0; s < VQ_NSPLIT; ++s) {
        unsigned a1 = pb1[(size_t)q * VQ_NSPLIT + s];
        unsigned a2 = pb2[(size_t)q * VQ_NSPLIT + s];
        unsigned ac = pcol[(size_t)q * VQ_NSPLIT + s];
        unsigned nb2 = umin_(umin_(B2, a2), umax_(B1, a1));
        if (a1 < B1) PAY = ((unsigned)s << 4) | ac;
        B1 = umin_(B1, a1); B2 = nb2;
    }
    const unsigned tile = B1 & 0xFFu;
    const unsigned code = (PAY >> 4) * VQ_KSPC + tile * 16 + (PAY & 15u);
    const float f1 = __uint_as_float(B1 & 0xFFFFFF00u);
    const float f2 = __uint_as_float(B2 & 0xFFFFFF00u);
    const int fl = (f2 - f1 < VQ_TAU_S) || (f1 < VQ_ABS_S);
    coarse[q] = code;
    flags[q] = (unsigned)fl;
    if (fl) { unsigned p = atomicAdd(counter, 1u); list[p] = q; }
}

// --- guard rescan: ONE WAVE per flagged query, no intra-loop barriers ------
__global__ __launch_bounds__(256)
void guard_k(const float* __restrict__ cb, const float* __restrict__ cbn_raw,
             const float* __restrict__ zz, const unsigned* __restrict__ list,
             const unsigned* __restrict__ counter, float2* __restrict__ gpart) {
    __shared__ float lcb[256 * 36];
    __shared__ float lnr[256];
    __shared__ int ns;

    const int tid = threadIdx.x;
    const int w = tid >> 6, ln = tid & 63;
    const int bx = blockIdx.x;

    const float4* cb4 = (const float4*)cb;
#pragma unroll
    for (int it = 0; it < 8; ++it) {
        const int f = tid + it * 256;
        float4 v = cb4[(size_t)bx * 2048 + f];
        const int c = f >> 3, g = f & 7;
        *(float4*)&lcb[c * 36 + g * 4] = v;
    }
    lnr[tid] = cbn_raw[bx * 256 + tid];
    if (tid == 0) ns = (int)*(volatile unsigned*)counter;
    __syncthreads();

    for (int ii = blockIdx.y * 4 + w; ii < ns; ii += 32) {
        const int q = (int)list[ii];
        const float4* zq = (const float4*)(zz + (size_t)q * 32);
        float m2[32];
#pragma unroll
        for (int j = 0; j < 8; ++j) {
            float4 v = zq[j];
            m2[j*4+0] = -2.f*v.x; m2[j*4+1] = -2.f*v.y; m2[j*4+2] = -2.f*v.z; m2[j*4+3] = -2.f*v.w;
        }
        float bv = FLT_MAX; int bc = 0x7FFFFFFF;
#pragma unroll
        for (int cc = 0; cc < 4; ++cc) {
            const int c = cc * 64 + ln;
            float d = lnr[c];
#pragma unroll
            for (int j = 0; j < 8; ++j) {
                float4 e = *(const float4*)&lcb[c * 36 + j * 4];
                d = fmaf(m2[j*4+0], e.x, d);
                d = fmaf(m2[j*4+1], e.y, d);
                d = fmaf(m2[j*4+2], e.z, d);
                d = fmaf(m2[j*4+3], e.w, d);
            }
            if (d < bv || (d == bv && c < bc)) { bv = d; bc = c; }
        }
#pragma unroll
        for (int m = 1; m < 64; m <<= 1) {
            float ov = __shfl_xor(bv, m, 64);
            int   oi = __shfl_xor(bc, m, 64);
            if (ov < bv || (ov == bv && oi < bc)) { bv = ov; bc = oi; }
        }
        if (ln == 0) gpart[(size_t)q * 256 + bx] = make_float2(bv, (float)(bx * 256 + bc));
    }
}

// --- final: ONE WAVE per query; parallel 256-entry gpart reduce ------------
__global__ __launch_bounds__(256)
void final_k(const unsigned* __restrict__ flags, const unsigned* __restrict__ coarse,
             const float2* __restrict__ gpart, const float* __restrict__ cb,
             float* __restrict__ out_idx, float* __restrict__ out_zq) {
    const int tid = threadIdx.x, w = tid >> 6, ln = tid & 63;
    const int q = blockIdx.x * 4 + w;
    int bi;
    if (flags[q]) {
        float bv = FLT_MAX; int bidx = 0x7FFFFFFF;
#pragma unroll
        for (int k = 0; k < 4; ++k) {
            const int b = k * 64 + ln;     // coalesced across lanes
            float2 o = gpart[(size_t)q * 256 + b];
            int oi = (int)o.y;
            if (o.x < bv || (o.x == bv && oi < bidx)) { bv = o.x; bidx = oi; }
        }
#pragma unroll
        for (int m = 1; m < 64; m <<= 1) {
            float ov = __shfl_xor(bv, m, 64);
            int   oi = __shfl_xor(bidx, m, 64);
            if (ov < bv || (ov == bv && oi < bidx)) { bv = ov; bidx = oi; }
        }
        bi = bidx;
    } else {
        bi = (int)coarse[q];
    }
    if (ln == 0) out_idx[q] = (float)bi;
    if (ln < 8) {
        float4 v = ((const float4*)(cb + (size_t)bi * 32))[ln];
        ((float4*)(out_zq + (size_t)q * 32))[ln] = v;
    }
}

// ---------------------------------------------------------------------------
extern "C" void kernel_launch(void* const* d_in, const int* in_sizes, int n_in,
                              void* d_out, int out_size, void* d_ws, size_t ws_size,
                              hipStream_t stream) {
    const float* x  = (const float*)d_in[0];
    const float* w1 = (const float*)d_in[1];
    const float* b1 = (const float*)d_in[2];
    const float* w2 = (const float*)d_in[3];
    const float* b2 = (const float*)d_in[4];
    const float* w3 = (const float*)d_in[5];
    const float* b3 = (const float*)d_in[6];
    const float* w4 = (const float*)d_in[7];
    const float* b4 = (const float*)d_in[8];
    const float* cb = (const float*)d_in[9];
    float* out = (float*)d_out;

    float* ws = (float*)d_ws;
    // Region A (conv phase: y1 planes; VQ phase: scratch + gpart)
    _Float16* y1h = (_Float16*)ws;
    _Float16* y1l = (_Float16*)(ws + 4460544);
    // Region B: y2 planes
    _Float16* y2h = (_Float16*)(ws + 8921088);
    _Float16* y2l = (_Float16*)(ws + 10104832);
    // Region C: y3 plane
    _Float16* y3h = (_Float16*)(ws + 11288576);
    _Float16* y3l = (_Float16*)(ws + 11584512);
    // Region D: zz fp32 NHWC
    float* zzp = ws + 11880448;
    // Region E: packed weights, one buffer pair per layer
    h8* B2h = (h8*)(ws + 12011520);   // 131072 f
    h8* B2l = (h8*)(ws + 12142592);   // 131072 f
    h8* B3h = (h8*)(ws + 12273664);   // 131072 f
    h8* B3l = (h8*)(ws + 12404736);   // 131072 f
    h8* B4h = (h8*)(ws + 12535808);   // 18432 f
    h8* B4l = (h8*)(ws + 12554240);   // 18432 f
    // Region F: conv partials (conv4 only now)
    float* part = ws + 12572672;      // 1048576 f -> ends 13621248 f (54.5 MB)
    // VQ scratch overlaying region A (y1 dead by then):
    h8*       cbh     = (h8*)ws;
    h8*       cbl     = (h8*)(ws + 1048576);
    h8*       zh      = (h8*)(ws + 2097152);
    h8*       zl      = (h8*)(ws + 2162688);
    float*    cbn2    = ws + 2228224;
    float*    cbn_raw = ws + 2293760;
    unsigned* pb1     = (unsigned*)(ws + 2359296);   // 262144 u32 (64 splits)
    unsigned* pb2     = (unsigned*)(ws + 2621440);
    unsigned* pcol    = (unsigned*)(ws + 2883584);
    unsigned* coarse  = (unsigned*)(ws + 3145728);
    unsigned* flags   = (unsigned*)(ws + 3149824);
    unsigned* list    = (unsigned*)(ws + 3153920);
    unsigned* counter = (unsigned*)(ws + 3158016);
    float2*   gpart   = (float2*)(ws + 3158080);     // 2097152 f -> ends 5255232

    // encoder
    zero_b_k<<<dim3(16, 6), 256, 0, stream>>>(y1h, y1l, y2h, y2l, y3h, y3l);
    pack3_k<<<dim3(128, 3), 256, 0, stream>>>(w2, w3, w4, B2h, B2l, B3h, B3l, B4h, B4l);
    conv1_k<<<dim3(64, 16, 4), 256, 0, stream>>>(x, w1, b1, y1h, y1l);
    // conv2: 512 blocks (2 m-waves x full N), reg-staged T14 weight pipeline
    gemmP_k<4, true><<<dim3(512), 256, 0, stream>>>(y1h, y1l, B2h, B2l, b2, y2h, y2l,
                                                    64, 64, 66, 34);
    // conv3: 256 blocks (1 m-wave x full N), same template, fused finalize
    gemmP_k<2, false><<<dim3(256), 256, 0, stream>>>(y2h, y2l, B3h, B3l, b3, y3h, y3l,
                                                     32, 32, 34, 34);
    gemm_k<1, false, 1, 1><<<dim3(64, 3), 256, 0, stream>>>(y3h, y3l, B4h, B4l, part, nullptr, nullptr, nullptr,
                                                            32, 32, 34, 2, 3, 4096, 32, 0);
    fin4_k<<<64, 256, 0, stream>>>(part, b4, zzp, zh, zl);

    // vector quantization
    split_cb_k<<<256, 256, 0, stream>>>(cb, cbh, cbl, cbn2, cbn_raw, counter);
    // 64 K-splits x 16 q-blocks: 1024 blocks, QT=4, best-measured config
    vq_mfma_k <<<dim3(16, VQ_NSPLIT), 256, 0, stream>>>(zh, zl, (const uint4*)cbh, (const uint4*)cbl,
                                                        cbn2, pb1, pb2, pcol);
    combine_k <<<16,  256, 0, stream>>>(pb1, pb2, pcol, coarse, flags, list, counter);
    // guard: wave-per-query (32 streams/block), no intra-loop barriers
    guard_k   <<<dim3(256, 8), 256, 0, stream>>>(cb, cbn_raw, zzp, list, counter, gpart);
    // final: wave-per-query parallel reduce over 256 guard partials
    final_k   <<<1024, 256, 0, stream>>>(flags, coarse, gpart, cb, out, out + 4096);
}

// Round 13
// 237.441 us; speedup vs baseline: 1.0608x; 1.0608x over previous
//
#include <hip/hip_runtime.h>
#include <cfloat>

typedef float f32x4 __attribute__((ext_vector_type(4)));
typedef _Float16 h8 __attribute__((ext_vector_type(8)));

static __device__ __forceinline__ unsigned umin_(unsigned a, unsigned b) { return a < b ? a : b; }
static __device__ __forceinline__ unsigned umax_(unsigned a, unsigned b) { return a > b ? a : b; }
// second-min update: med3(b1, b2, k) == min(b2, max(k, b1)) given b1 <= b2
static __device__ __forceinline__ unsigned med3_(unsigned a, unsigned b, unsigned c) {
    unsigned d;
    asm("v_med3_u32 %0, %1, %2, %3" : "=v"(d) : "v"(a), "v"(b), "v"(c));
    return d;
}

// async global->LDS, 16B per lane; LDS dest = wave-uniform base + lane*16
static __device__ __forceinline__ void gl_lds16(const h8* g, h8* s) {
    __builtin_amdgcn_global_load_lds(
        (const __attribute__((address_space(1))) unsigned int*)g,
        (__attribute__((address_space(3))) unsigned int*)s, 16, 0, 0);
}

// ===========================================================================
// Fused preprocessing: plane zero-fill + weight pack (both pre-conv safe).
//   bx <  96 : zero-fill padded activation plane borders
//   96..479  : pack w2/w3/w4 into fragment-ordered fp16 hi/lo
// (codebook split stays in the VQ phase: its buffers overlay the y1 region,
//  which is only dead AFTER the conv stack -- R11's crash was moving it here.)
// ===========================================================================
__global__ __launch_bounds__(256)
void prep_k(_Float16* p0, _Float16* p1, _Float16* p2, _Float16* p3,
            _Float16* p4, _Float16* p5,
            const float* __restrict__ w2, const float* __restrict__ w3,
            const float* __restrict__ w4,
            h8* __restrict__ B2h, h8* __restrict__ B2l,
            h8* __restrict__ B3h, h8* __restrict__ B3l,
            h8* __restrict__ B4h, h8* __restrict__ B4l) {
    const int bx = blockIdx.x;
    const int tid = threadIdx.x;

    if (bx < 96) {
        // ---- job A: zero-fill plane borders ----
        const int s = bx >> 4, plane = bx & 15;
        _Float16* p; int np, P;
        switch (s) {
            case 0: p = p0; np = 16; P = 66; break;
            case 1: p = p1; np = 16; P = 66; break;
            case 2: p = p2; np = 16; P = 34; break;
            case 3: p = p3; np = 16; P = 34; break;
            case 4: p = p4; np = 4;  P = 34; break;
            default: p = p5; np = 4; P = 34; break;
        }
        if (plane >= np) return;
        _Float16* pl = p + (size_t)plane * P * P * 128;
        const int rowN = P * 128;
        for (int i = tid; i < rowN; i += 256) {
            pl[i] = (_Float16)0.f;
            pl[(size_t)(P - 1) * rowN + i] = (_Float16)0.f;
            const int r = i >> 7, c = i & 127;
            pl[(size_t)r * rowN + c] = (_Float16)0.f;
            pl[(size_t)r * rowN + (P - 1) * 128 + c] = (_Float16)0.f;
        }
    } else {
        // ---- job B: pack conv weights ----
        const int layer = (bx - 96) >> 7;
        const int bxx = (bx - 96) & 127;
        const float* w; h8 *Bh, *Bl; int T, NT, KHKW;
        switch (layer) {
            case 0:  w = w2; Bh = B2h; Bl = B2l; T = 16; NT = 8; KHKW = 16; break;
            case 1:  w = w3; Bh = B3h; Bl = B3l; T = 16; NT = 8; KHKW = 16; break;
            default: w = w4; Bh = B4h; Bl = B4l; T = 9;  NT = 2; KHKW = 9;  break;
        }
        const int idx = bxx * 256 + tid;
        if (idx >= T * 4 * NT * 64) return;
        const int lane = idx & 63;
        int r = idx >> 6;
        const int nt = r % NT; r /= NT;
        const int ks = r & 3;  r >>= 2;
        const int t = r;
        const int oc = nt * 16 + (lane & 15);
        const int icb = ks * 32 + (lane >> 4) * 8;
        h8 hv, lv;
#pragma unroll
        for (int j = 0; j < 8; ++j) {
            const float v = w[(size_t)(oc * 128 + icb + j) * KHKW + t];
            _Float16 h = (_Float16)v;
            hv[j] = h;
            lv[j] = (_Float16)((v - (float)h) * 2048.f);
        }
        Bh[idx] = hv;
        Bl[idx] = lv;
    }
}

// --- conv1: fp32 direct (IC=3), writes split planes ------------------------
__global__ __launch_bounds__(256)
void conv1_k(const float* __restrict__ in, const float* __restrict__ w,
             const float* __restrict__ bias,
             _Float16* __restrict__ Dh, _Float16* __restrict__ Dl) {
    __shared__ float tile[3][34 * 36];
    const int tid = threadIdx.x;
    const int tx = tid & 15, ty = tid >> 4;
    const int bx = blockIdx.x & 7, by = blockIdx.x >> 3;
    const int oc0 = blockIdx.y * 8;
    const int b = blockIdx.z;
    const int ox = bx * 16 + tx, oy = by * 16 + ty;
    const int ix0 = bx * 32 - 1, iy0 = by * 32 - 1;

    for (int f = tid; f < 3 * 34 * 34; f += 256) {
        const int ic = f / 1156, r2 = f % 1156;
        const int r = r2 / 34, c = r2 % 34;
        const int iy = iy0 + r, ix = ix0 + c;
        float v = ((unsigned)iy < 256u && (unsigned)ix < 256u)
                      ? in[((size_t)(b * 3 + ic) * 256 + iy) * 256 + ix] : 0.f;
        tile[ic][r * 36 + c] = v;
    }
    __syncthreads();

    float acc[8];
#pragma unroll
    for (int j = 0; j < 8; ++j) acc[j] = 0.f;
#pragma unroll
    for (int ic = 0; ic < 3; ++ic) {
#pragma unroll
        for (int kh = 0; kh < 4; ++kh) {
            const float2* p = (const float2*)&tile[ic][(2 * ty + kh) * 36 + 2 * tx];
            const float2 r0 = p[0], r1 = p[1];
            const float tap[4] = {r0.x, r0.y, r1.x, r1.y};
#pragma unroll
            for (int kw = 0; kw < 4; ++kw)
#pragma unroll
                for (int j = 0; j < 8; ++j)
                    acc[j] = fmaf(tap[kw], w[((oc0 + j) * 3 + ic) * 16 + kh * 4 + kw], acc[j]);
        }
    }

    h8 hv, lv;
#pragma unroll
    for (int j = 0; j < 8; ++j) {
        float r = fmaxf(acc[j] + bias[oc0 + j], 0.f);
        _Float16 h = (_Float16)r;
        hv[j] = h;
        lv[j] = (_Float16)((r - (float)h) * 2048.f);
    }
    const size_t di = (((size_t)((b * 2 + (oy & 1)) * 2 + (ox & 1)) * 66 + 1 + (oy >> 1)) * 66
                       + 1 + (ox >> 1)) * 128 + oc0;
    *(h8*)(Dh + di) = hv;
    *(h8*)(Dl + di) = lv;
}

// --- stride-2 tap-GEMM, double-buffered LDS weights (conv2, conv3) ---------
template<int WN, int MT, bool SPLIT>
__global__ __launch_bounds__(256, 1)
void gemmS2_k(const _Float16* __restrict__ Ah, const _Float16* __restrict__ Al,
              const h8* __restrict__ Bh, const h8* __restrict__ Bl,
              const float* __restrict__ bias,
              _Float16* __restrict__ Dh, _Float16* __restrict__ Dl,
              int OW, int OH, int PP, int dPP) {
    constexpr int NW_N = 8 / WN;     // waves along N
    constexpr int NW_M = 4 / NW_N;   // m-waves per block
    __shared__ h8 lH[2][2048];       // 2 x 32 KB: tap slab hi
    __shared__ h8 lL[2][2048];       // 2 x 32 KB: tap slab lo

    const int tid = threadIdx.x, wid = tid >> 6, l = tid & 63;
    const int nq = wid % NW_N, mi = wid / NW_N;
    const int mt0 = (blockIdx.x * NW_M + mi) * MT;
    const int mpr = OW >> 4, mpi = OH * mpr;
    const int laneA = (l & 15) * 128 + (l >> 4) * 8;

    int bm[MT], oym[MT], oxm[MT];
#pragma unroll
    for (int m = 0; m < MT; ++m) {
        const int mt = mt0 + m;
        bm[m] = mt / mpi;
        const int rem = mt % mpi;
        oym[m] = rem / mpr;
        oxm[m] = (rem % mpr) << 4;
    }

    f32x4 a1[MT][WN], am[MT][WN];
#pragma unroll
    for (int m = 0; m < MT; ++m)
#pragma unroll
        for (int s = 0; s < WN; ++s) {
            a1[m][s] = (f32x4){0.f, 0.f, 0.f, 0.f};
            am[m][s] = (f32x4){0.f, 0.f, 0.f, 0.f};
        }

    // prologue: stage tap 0 into slab 0 (each wave moves a 16 KB chunk)
    {
        const h8* sh = Bh + wid * 512 + l;
        const h8* sl = Bl + wid * 512 + l;
#pragma unroll
        for (int i = 0; i < 8; ++i) gl_lds16(sh + i * 64, &lH[0][wid * 512 + i * 64]);
#pragma unroll
        for (int i = 0; i < 8; ++i) gl_lds16(sl + i * 64, &lL[0][wid * 512 + i * 64]);
    }
    __syncthreads();

#pragma unroll 1
    for (int t = 0; t < 16; ++t) {
        const int cur = t & 1;
        // A fragments for tap t into regs — issued FIRST
        const int kh = t >> 2, kw = t & 3;
        const int dy = (kh - 1) >> 1, dx = (kw - 1) >> 1;
        const int py = (kh - 1) & 1, px = (kw - 1) & 1;
        h8 avh[MT][4], avl[MT][4];
#pragma unroll
        for (int m = 0; m < MT; ++m) {
            const int pidx = (bm[m] * 2 + py) * 2 + px;
            const size_t abase = ((size_t)(pidx * PP + (oym[m] + dy + 1)) * PP
                                  + (oxm[m] + dx + 1)) * 128 + laneA;
#pragma unroll
            for (int ks = 0; ks < 4; ++ks) {
                avh[m][ks] = *(const h8*)(Ah + abase + ks * 32);
                avl[m][ks] = *(const h8*)(Al + abase + ks * 32);
            }
        }
        // async-stage tap t+1 into the alternate slab (in flight under compute)
        if (t + 1 < 16) {
            const int nxt = cur ^ 1;
            const h8* sh = Bh + (size_t)(t + 1) * 2048 + wid * 512 + l;
            const h8* sl = Bl + (size_t)(t + 1) * 2048 + wid * 512 + l;
#pragma unroll
            for (int i = 0; i < 8; ++i) gl_lds16(sh + i * 64, &lH[nxt][wid * 512 + i * 64]);
#pragma unroll
            for (int i = 0; i < 8; ++i) gl_lds16(sl + i * 64, &lL[nxt][wid * 512 + i * 64]);
        }
        // compute on slab[cur] (ready since previous barrier)
#pragma unroll
        for (int ks = 0; ks < 4; ++ks) {
#pragma unroll
            for (int s = 0; s < WN; ++s) {
                const h8 bvh = lH[cur][(ks * 8 + nq * WN + s) * 64 + l];
                const h8 bvl = lL[cur][(ks * 8 + nq * WN + s) * 64 + l];
#pragma unroll
                for (int m = 0; m < MT; ++m) {
                    a1[m][s] = __builtin_amdgcn_mfma_f32_16x16x32_f16(avh[m][ks], bvh, a1[m][s], 0, 0, 0);
                    am[m][s] = __builtin_amdgcn_mfma_f32_16x16x32_f16(avh[m][ks], bvl, am[m][s], 0, 0, 0);
                    am[m][s] = __builtin_amdgcn_mfma_f32_16x16x32_f16(avl[m][ks], bvh, am[m][s], 0, 0, 0);
                }
            }
        }
        __syncthreads();   // drains stage(t+1); releases slab[cur] for t+2
    }

    // fused finalize: bias + relu + hi/lo split
#pragma unroll
    for (int m = 0; m < MT; ++m) {
#pragma unroll
        for (int s = 0; s < WN; ++s) {
            const int oc = (nq * WN + s) * 16 + (l & 15);
            const float bv = bias[oc];
#pragma unroll
            for (int i = 0; i < 4; ++i) {
                const int row = (l >> 4) * 4 + i;
                float v = fmaf(am[m][s][i], 4.8828125e-4f, a1[m][s][i]);
                v = fmaxf(v + bv, 0.f);
                _Float16 h = (_Float16)v;
                _Float16 lo = (_Float16)((v - (float)h) * 2048.f);
                const int oxp = oxm[m] + row;
                const int oy = oym[m], b = bm[m];
                size_t di;
                if constexpr (SPLIT) {
                    di = (((size_t)((b * 2 + (oy & 1)) * 2 + (oxp & 1)) * dPP
                           + 1 + (oy >> 1)) * dPP + 1 + (oxp >> 1)) * 128 + oc;
                } else {
                    di = ((size_t)(b * dPP + 1 + oy) * dPP + 1 + oxp) * 128 + oc;
                }
                Dh[di] = h;
                Dl[di] = lo;
            }
        }
    }
}

// --- universal tap-GEMM conv (3-term fp16-split MFMA) — kept for conv4 -----
template<int S, bool FIN, int WPN, int MT>
__global__ __launch_bounds__(256)
void gemm_k(const _Float16* __restrict__ Ah, const _Float16* __restrict__ Al,
            const h8* __restrict__ Bh, const h8* __restrict__ Bl,
            float* __restrict__ part, const float* __restrict__ bias,
            _Float16* __restrict__ Dh, _Float16* __restrict__ Dl,
            int OW, int OH, int PP, int NT, int TPS, int M, int N, int dPP) {
    const int tid = threadIdx.x, wid = tid >> 6, l = tid & 63;
    const int ntb = wid % WPN;
    const int mt0 = (blockIdx.x * (4 / WPN) + wid / WPN) * MT;
    const int sp = blockIdx.y;
    const int mpr = OW >> 4, mpi = OH * mpr;
    const int laneA = (l & 15) * 128 + (l >> 4) * 8;

    int bmt[MT], oymt[MT], oxmt[MT];
#pragma unroll
    for (int m = 0; m < MT; ++m) {
        const int mt = mt0 + m;
        bmt[m] = mt / mpi;
        const int rem = mt % mpi;
        oymt[m] = rem / mpr;
        oxmt[m] = (rem % mpr) << 4;
    }

    f32x4 a1[MT][2], am[MT][2];
#pragma unroll
    for (int m = 0; m < MT; ++m)
#pragma unroll
        for (int s = 0; s < 2; ++s) {
            a1[m][s] = (f32x4){0.f, 0.f, 0.f, 0.f};
            am[m][s] = (f32x4){0.f, 0.f, 0.f, 0.f};
        }

    const int t0 = sp * TPS, t1 = t0 + TPS;
#pragma unroll 2
    for (int t = t0; t < t1; ++t) {
        int dy, dx, pidx[MT];
        if constexpr (S == 2) {
            const int kh = t >> 2, kw = t & 3;
            dy = (kh - 1) >> 1; dx = (kw - 1) >> 1;
            const int py = (kh - 1) & 1, px = (kw - 1) & 1;
#pragma unroll
            for (int m = 0; m < MT; ++m) pidx[m] = (bmt[m] * 2 + py) * 2 + px;
        } else {
            dy = t / 3 - 1; dx = t % 3 - 1;
#pragma unroll
            for (int m = 0; m < MT; ++m) pidx[m] = bmt[m];
        }
        const _Float16* pAh[MT]; const _Float16* pAl[MT];
#pragma unroll
        for (int m = 0; m < MT; ++m) {
            const size_t base = ((size_t)(pidx[m] * PP + (oymt[m] + dy + 1)) * PP
                                 + (oxmt[m] + dx + 1)) * 128 + laneA;
            pAh[m] = Ah + base;
            pAl[m] = Al + base;
        }
        const size_t bbase = ((size_t)(t * 4) * NT + ntb * 2) * 64 + l;
#pragma unroll
        for (int ks = 0; ks < 4; ++ks) {
            h8 avh[MT], avl[MT];
#pragma unroll
            for (int m = 0; m < MT; ++m) {
                avh[m] = *(const h8*)(pAh[m] + ks * 32);
                avl[m] = *(const h8*)(pAl[m] + ks * 32);
            }
#pragma unroll
            for (int s = 0; s < 2; ++s) {
                const h8 bvh = Bh[bbase + (size_t)ks * NT * 64 + s * 64];
                const h8 bvl = Bl[bbase + (size_t)ks * NT * 64 + s * 64];
#pragma unroll
                for (int m = 0; m < MT; ++m) {
                    a1[m][s] = __builtin_amdgcn_mfma_f32_16x16x32_f16(avh[m], bvh, a1[m][s], 0, 0, 0);
                    am[m][s] = __builtin_amdgcn_mfma_f32_16x16x32_f16(avh[m], bvl, am[m][s], 0, 0, 0);
                    am[m][s] = __builtin_amdgcn_mfma_f32_16x16x32_f16(avl[m], bvh, am[m][s], 0, 0, 0);
                }
            }
        }
    }

#pragma unroll
    for (int m = 0; m < MT; ++m) {
        const int mt = mt0 + m;
#pragma unroll
        for (int s = 0; s < 2; ++s) {
            const int oc = ntb * 32 + s * 16 + (l & 15);
#pragma unroll
            for (int i = 0; i < 4; ++i) {
                const int row = (l >> 4) * 4 + i;
                float v = fmaf(am[m][s][i], 4.8828125e-4f, a1[m][s][i]);
                if (!FIN) {
                    part[((size_t)sp * M + mt * 16 + row) * N + oc] = v;
                } else {
                    v = fmaxf(v + bias[oc], 0.f);
                    _Float16 h = (_Float16)v;
                    _Float16 lo = (_Float16)((v - (float)h) * 2048.f);
                    const int ox = oxmt[m] + row;
                    const int oy = oymt[m], b = bmt[m];
                    const size_t di = (((size_t)((b * 2 + (oy & 1)) * 2 + (ox & 1)) * dPP
                                        + 1 + (oy >> 1)) * dPP + 1 + (ox >> 1)) * 128 + oc;
                    Dh[di] = h;
                    Dl[di] = lo;
                }
            }
        }
    }
}

// --- conv4 finalize + fused z-split: 3 partials + bias -> zz fp32 + frags --
// zh = fp16 hi of (-2z); zl = UNSCALED fp16 lo (vq uses scaled-hi codebook).
__global__ __launch_bounds__(256)
void fin4_k(const float* __restrict__ part, const float* __restrict__ bias,
            float* __restrict__ zz, h8* __restrict__ zh, h8* __restrict__ zl) {
    const int t = blockIdx.x * 256 + threadIdx.x;
    const int m = t >> 2, g8 = (t & 3) * 8;
    float v[8];
#pragma unroll
    for (int j = 0; j < 8; ++j) v[j] = bias[g8 + j];
#pragma unroll
    for (int sp = 0; sp < 3; ++sp) {
        const float4* p = (const float4*)(part + ((size_t)sp * 4096 + m) * 32 + g8);
        float4 x0 = p[0], x1 = p[1];
        v[0] += x0.x; v[1] += x0.y; v[2] += x0.z; v[3] += x0.w;
        v[4] += x1.x; v[5] += x1.y; v[6] += x1.z; v[7] += x1.w;
    }
    float4* dst = (float4*)(zz + (size_t)m * 32 + g8);
    dst[0] = make_float4(v[0], v[1], v[2], v[3]);
    dst[1] = make_float4(v[4], v[5], v[6], v[7]);
    // fused split_z: A-fragment order, value = -2z, hi + UNSCALED lo
    h8 hv, lv;
#pragma unroll
    for (int j = 0; j < 8; ++j) {
        const float mv = -2.f * v[j];
        _Float16 h = (_Float16)mv;
        hv[j] = h;
        lv[j] = (_Float16)(mv - (float)h);
    }
    const int idx = (m >> 4) * 64 + (m & 15) + (t & 3) * 16;
    zh[idx] = hv;
    zl[idx] = lv;
}

// ===========================================================================
// VQ: fp16-split MFMA coarse argmin + certified-margin fp32 guard rescan.
// Scaled-fold scheme: codebook-hi stored as eh*2048, z-lo stored unscaled.
// acc = (nrm+512)*2048 + zh*(eh*2048) + zh*(el*2048) + zl_u*(eh*2048)
//     = 2048 * d0  -> min-tracking directly on acc bits (monotone).
// ===========================================================================
#define VQ_NSPLIT 64
#define VQ_KSPC   1024
#define VQ_NCHUNK 8             /* 128 codes per chunk */
#define VQ_TAU_S  102.4f        /* 0.05 * 2048 */
#define VQ_ABS_S  524288.0f     /* 256  * 2048 */
#define VQ_QT     4

__global__ __launch_bounds__(256)
void split_cb_k(const float* __restrict__ cb, h8* __restrict__ cbh, h8* __restrict__ cbl,
                float* __restrict__ cbn2, float* __restrict__ cbn_raw,
                unsigned* __restrict__ counter) {
    const int c = blockIdx.x * 256 + threadIdx.x;
    const float4* p = (const float4*)(cb + (size_t)c * 32);
    float e[32];
    float s = 0.f;
#pragma unroll
    for (int i = 0; i < 8; ++i) {
        float4 v = p[i];
        e[i*4+0] = v.x; e[i*4+1] = v.y; e[i*4+2] = v.z; e[i*4+3] = v.w;
        s += v.x*v.x + v.y*v.y + v.z*v.z + v.w*v.w;
    }
    cbn_raw[c] = s;
    cbn2[c]    = (s + 512.0f) * 2048.0f;   // pre-scaled accumulator init
    const int base = (c >> 4) * 64 + (c & 15);
#pragma unroll
    for (int g = 0; g < 4; ++g) {
        h8 hv, lv;
#pragma unroll
        for (int j = 0; j < 8; ++j) {
            float v = e[g*8 + j];
            _Float16 h = (_Float16)v;
            hv[j] = (_Float16)((float)h * 2048.0f);   // scaled hi (exact pow2)
            lv[j] = (_Float16)((v - (float)h) * 2048.0f);
        }
        cbh[base + g*16] = hv;
        cbl[base + g*16] = lv;
    }
    if (c == 0) *counter = 0u;
}

// --- coarse MFMA pass: VQ_QT q-tiles per wave, single scaled accumulator ---
__global__ __launch_bounds__(256, 4)
void vq_mfma_k(const h8* __restrict__ zh, const h8* __restrict__ zl,
               const uint4* __restrict__ cbh, const uint4* __restrict__ cbl,
               const float* __restrict__ cbn2,
               unsigned* __restrict__ pb1, unsigned* __restrict__ pb2,
               unsigned* __restrict__ pcol) {
    __shared__ uint4 lH[2][512];
    __shared__ uint4 lL[2][512];
    __shared__ float lN[2][128];

    const int tid = threadIdx.x;
    const int w = tid >> 6, ln = tid & 63;
    const int split = blockIdx.y;
    const int qt0 = (blockIdx.x * 4 + w) * VQ_QT;   // first q-tile of this wave

    h8 azh[VQ_QT], azl[VQ_QT];
#pragma unroll
    for (int qq = 0; qq < VQ_QT; ++qq) {
        azh[qq] = zh[(qt0 + qq) * 64 + ln];
        azl[qq] = zl[(qt0 + qq) * 64 + ln];
    }

    unsigned b1[VQ_QT][4], b2[VQ_QT][4];
#pragma unroll
    for (int qq = 0; qq < VQ_QT; ++qq)
#pragma unroll
        for (int i = 0; i < 4; ++i) { b1[qq][i] = 0x7F800000u; b2[qq][i] = 0x7F800000u; }

    const int fbase = split * (VQ_KSPC * 4);
    const int nbase = split * VQ_KSPC;

    // prologue: stage chunk 0
    {
        uint4 h0 = cbh[fbase + tid], h1 = cbh[fbase + 256 + tid];
        uint4 l0 = cbl[fbase + tid], l1 = cbl[fbase + 256 + tid];
        lH[0][tid] = h0; lH[0][tid + 256] = h1;
        lL[0][tid] = l0; lL[0][tid + 256] = l1;
        if (tid < 128) lN[0][tid] = cbn2[nbase + tid];
    }
    __syncthreads();

    for (int ci = 0; ci < VQ_NCHUNK; ++ci) {
        const int cur = ci & 1;
        const bool more = (ci + 1 < VQ_NCHUNK);
        uint4 nh0, nh1, nl0, nl1; float nn = 0.f;
        if (more) {
            const int nb = fbase + (ci + 1) * 512;
            nh0 = cbh[nb + tid]; nh1 = cbh[nb + 256 + tid];
            nl0 = cbl[nb + tid]; nl1 = cbl[nb + 256 + tid];
            if (tid < 128) nn = cbn2[nbase + (ci + 1) * 128 + tid];
        }

        const unsigned tcb = (unsigned)(ci * 8);
#pragma unroll
        for (int t = 0; t < 8; ++t) {
            const h8 bh = *reinterpret_cast<const h8*>(&lH[cur][t*64 + ln]);
            const h8 bl = *reinterpret_cast<const h8*>(&lL[cur][t*64 + ln]);
            const float nv = lN[cur][t*16 + (ln & 15)];   // (nrm+512)*2048
            f32x4 nvv = {nv, nv, nv, nv};                 // shared C-operand
            const unsigned tc = tcb + t;
#pragma unroll
            for (int qq = 0; qq < VQ_QT; ++qq) {
                f32x4 acc;
                acc = __builtin_amdgcn_mfma_f32_16x16x32_f16(azh[qq], bh, nvv, 0, 0, 0);
                acc = __builtin_amdgcn_mfma_f32_16x16x32_f16(azh[qq], bl, acc, 0, 0, 0);
                acc = __builtin_amdgcn_mfma_f32_16x16x32_f16(azl[qq], bh, acc, 0, 0, 0);
#pragma unroll
                for (int i = 0; i < 4; ++i) {
                    const unsigned k0 = (__float_as_uint(acc[i]) & 0xFFFFFF00u) | tc;
                    b2[qq][i] = med3_(b1[qq][i], b2[qq][i], k0);   // second-min
                    b1[qq][i] = umin_(b1[qq][i], k0);
                }
            }
        }

        if (more) {
            const int nxt = cur ^ 1;
            lH[nxt][tid] = nh0; lH[nxt][tid + 256] = nh1;
            lL[nxt][tid] = nl0; lL[nxt][tid + 256] = nl1;
            if (tid < 128) lN[nxt][tid] = nn;
        }
        __syncthreads();   // writes to nxt visible; all reads of cur complete
    }

    // reduce over the 16 code-columns (lane bits 0..3); ties -> min idx
#pragma unroll
    for (int qq = 0; qq < VQ_QT; ++qq) {
#pragma unroll
        for (int i = 0; i < 4; ++i) {
            unsigned v1 = b1[qq][i], v2 = b2[qq][i], cv = (unsigned)(ln & 15);
#pragma unroll
            for (int m = 1; m < 16; m <<= 1) {
                unsigned o1 = __shfl_xor(v1, m, 64);
                unsigned o2 = __shfl_xor(v2, m, 64);
                unsigned oc = __shfl_xor(cv, m, 64);
                unsigned nb2 = umin_(umin_(v2, o2), umax_(v1, o1));
                if (o1 < v1) cv = oc;
                v1 = umin_(v1, o1); v2 = nb2;
            }
            if ((ln & 15) == 0) {
                const int q = (qt0 + qq) * 16 + (ln >> 4) * 4 + i;
                pb1[(size_t)q * VQ_NSPLIT + split] = v1;
                pb2[(size_t)q * VQ_NSPLIT + split] = v2;
                pcol[(size_t)q * VQ_NSPLIT + split] = cv;
            }
        }
    }
}

__global__ __launch_bounds__(256)
void combine_k(const unsigned* __restrict__ pb1, const unsigned* __restrict__ pb2,
               const unsigned* __restrict__ pcol,
               unsigned* __restrict__ coarse, unsigned* __restrict__ flags,
               unsigned* __restrict__ list, unsigned* __restrict__ counter) {
    const int q = blockIdx.x * 256 + threadIdx.x;
    unsigned B1 = 0x7F800000u, B2 = 0x7F800000u, PAY = 0u;
#pragma unroll 4
    for (int s = 0; s < VQ_NSPLIT; ++s) {
        unsigned a1 = pb1[(size_t)q * VQ_NSPLIT + s];
        unsigned a2 = pb2[(size_t)q * VQ_NSPLIT + s];
        unsigned ac = pcol[(size_t)q * VQ_NSPLIT + s];
        unsigned nb2 = umin_(umin_(B2, a2), umax_(B1, a1));
        if (a1 < B1) PAY = ((unsigned)s << 4) | ac;
        B1 = umin_(B1, a1); B2 = nb2;
    }
    const unsigned tile = B1 & 0xFFu;
    const unsigned code = (PAY >> 4) * VQ_KSPC + tile * 16 + (PAY & 15u);
    const float f1 = __uint_as_float(B1 & 0xFFFFFF00u);
    const float f2 = __uint_as_float(B2 & 0xFFFFFF00u);
    const int fl = (f2 - f1 < VQ_TAU_S) || (f1 < VQ_ABS_S);
    coarse[q] = code;
    flags[q] = (unsigned)fl;
    if (fl) { unsigned p = atomicAdd(counter, 1u); list[p] = q; }
}

// --- guard rescan: ONE WAVE per flagged query, no intra-loop barriers ------
__global__ __launch_bounds__(256)
void guard_k(const float* __restrict__ cb, const float* __restrict__ cbn_raw,
             const float* __restrict__ zz, const unsigned* __restrict__ list,
             const unsigned* __restrict__ counter, float2* __restrict__ gpart) {
    __shared__ float lcb[256 * 36];
    __shared__ float lnr[256];
    __shared__ int ns;

    const int tid = threadIdx.x;
    const int w = tid >> 6, ln = tid & 63;
    const int bx = blockIdx.x;

    const float4* cb4 = (const float4*)cb;
#pragma unroll
    for (int it = 0; it < 8; ++it) {
        const int f = tid + it * 256;
        float4 v = cb4[(size_t)bx * 2048 + f];
        const int c = f >> 3, g = f & 7;
        *(float4*)&lcb[c * 36 + g * 4] = v;
    }
    lnr[tid] = cbn_raw[bx * 256 + tid];
    if (tid == 0) ns = (int)*(volatile unsigned*)counter;
    __syncthreads();

    for (int ii = blockIdx.y * 4 + w; ii < ns; ii += 32) {
        const int q = (int)list[ii];
        const float4* zq = (const float4*)(zz + (size_t)q * 32);
        float m2[32];
#pragma unroll
        for (int j = 0; j < 8; ++j) {
            float4 v = zq[j];
            m2[j*4+0] = -2.f*v.x; m2[j*4+1] = -2.f*v.y; m2[j*4+2] = -2.f*v.z; m2[j*4+3] = -2.f*v.w;
        }
        float bv = FLT_MAX; int bc = 0x7FFFFFFF;
#pragma unroll
        for (int cc = 0; cc < 4; ++cc) {
            const int c = cc * 64 + ln;
            float d = lnr[c];
#pragma unroll
            for (int j = 0; j < 8; ++j) {
                float4 e = *(const float4*)&lcb[c * 36 + j * 4];
                d = fmaf(m2[j*4+0], e.x, d);
                d = fmaf(m2[j*4+1], e.y, d);
                d = fmaf(m2[j*4+2], e.z, d);
                d = fmaf(m2[j*4+3], e.w, d);
            }
            if (d < bv || (d == bv && c < bc)) { bv = d; bc = c; }
        }
#pragma unroll
        for (int m = 1; m < 64; m <<= 1) {
            float ov = __shfl_xor(bv, m, 64);
            int   oi = __shfl_xor(bc, m, 64);
            if (ov < bv || (ov == bv && oi < bc)) { bv = ov; bc = oi; }
        }
        if (ln == 0) gpart[(size_t)q * 256 + bx] = make_float2(bv, (float)(bx * 256 + bc));
    }
}

// --- final: ONE WAVE per query; parallel 256-entry gpart reduce ------------
__global__ __launch_bounds__(256)
void final_k(const unsigned* __restrict__ flags, const unsigned* __restrict__ coarse,
             const float2* __restrict__ gpart, const float* __restrict__ cb,
             float* __restrict__ out_idx, float* __restrict__ out_zq) {
    const int tid = threadIdx.x, w = tid >> 6, ln = tid & 63;
    const int q = blockIdx.x * 4 + w;
    int bi;
    if (flags[q]) {
        float bv = FLT_MAX; int bidx = 0x7FFFFFFF;
#pragma unroll
        for (int k = 0; k < 4; ++k) {
            const int b = k * 64 + ln;     // coalesced across lanes
            float2 o = gpart[(size_t)q * 256 + b];
            int oi = (int)o.y;
            if (o.x < bv || (o.x == bv && oi < bidx)) { bv = o.x; bidx = oi; }
        }
#pragma unroll
        for (int m = 1; m < 64; m <<= 1) {
            float ov = __shfl_xor(bv, m, 64);
            int   oi = __shfl_xor(bidx, m, 64);
            if (ov < bv || (ov == bv && oi < bidx)) { bv = ov; bidx = oi; }
        }
        bi = bidx;
    } else {
        bi = (int)coarse[q];
    }
    if (ln == 0) out_idx[q] = (float)bi;
    if (ln < 8) {
        float4 v = ((const float4*)(cb + (size_t)bi * 32))[ln];
        ((float4*)(out_zq + (size_t)q * 32))[ln] = v;
    }
}

// ---------------------------------------------------------------------------
extern "C" void kernel_launch(void* const* d_in, const int* in_sizes, int n_in,
                              void* d_out, int out_size, void* d_ws, size_t ws_size,
                              hipStream_t stream) {
    const float* x  = (const float*)d_in[0];
    const float* w1 = (const float*)d_in[1];
    const float* b1 = (const float*)d_in[2];
    const float* w2 = (const float*)d_in[3];
    const float* b2 = (const float*)d_in[4];
    const float* w3 = (const float*)d_in[5];
    const float* b3 = (const float*)d_in[6];
    const float* w4 = (const float*)d_in[7];
    const float* b4 = (const float*)d_in[8];
    const float* cb = (const float*)d_in[9];
    float* out = (float*)d_out;

    float* ws = (float*)d_ws;
    // Region A (conv phase: y1 planes; VQ phase: scratch + gpart)
    _Float16* y1h = (_Float16*)ws;
    _Float16* y1l = (_Float16*)(ws + 4460544);
    // Region B: y2 planes
    _Float16* y2h = (_Float16*)(ws + 8921088);
    _Float16* y2l = (_Float16*)(ws + 10104832);
    // Region C: y3 plane
    _Float16* y3h = (_Float16*)(ws + 11288576);
    _Float16* y3l = (_Float16*)(ws + 11584512);
    // Region D: zz fp32 NHWC
    float* zzp = ws + 11880448;
    // Region E: packed weights, one buffer pair per layer
    h8* B2h = (h8*)(ws + 12011520);   // 131072 f
    h8* B2l = (h8*)(ws + 12142592);   // 131072 f
    h8* B3h = (h8*)(ws + 12273664);   // 131072 f
    h8* B3l = (h8*)(ws + 12404736);   // 131072 f
    h8* B4h = (h8*)(ws + 12535808);   // 18432 f
    h8* B4l = (h8*)(ws + 12554240);   // 18432 f
    // Region F: conv partials (conv4 only now)
    float* part = ws + 12572672;      // 1048576 f -> ends 13621248 f (54.5 MB)
    // VQ scratch overlaying region A (y1 dead by then):
    h8*       cbh     = (h8*)ws;
    h8*       cbl     = (h8*)(ws + 1048576);
    h8*       zh      = (h8*)(ws + 2097152);
    h8*       zl      = (h8*)(ws + 2162688);
    float*    cbn2    = ws + 2228224;
    float*    cbn_raw = ws + 2293760;
    unsigned* pb1     = (unsigned*)(ws + 2359296);   // 262144 u32 (64 splits)
    unsigned* pb2     = (unsigned*)(ws + 2621440);
    unsigned* pcol    = (unsigned*)(ws + 2883584);
    unsigned* coarse  = (unsigned*)(ws + 3145728);
    unsigned* flags   = (unsigned*)(ws + 3149824);
    unsigned* list    = (unsigned*)(ws + 3153920);
    unsigned* counter = (unsigned*)(ws + 3158016);
    float2*   gpart   = (float2*)(ws + 3158080);     // 2097152 f -> ends 5255232

    // fused preprocessing: zero-fill + weight pack (1 launch, pre-conv safe)
    prep_k<<<480, 256, 0, stream>>>(y1h, y1l, y2h, y2l, y3h, y3l,
                                    w2, w3, w4, B2h, B2l, B3h, B3l, B4h, B4l);
    conv1_k<<<dim3(64, 16, 4), 256, 0, stream>>>(x, w1, b1, y1h, y1l);
    // conv2: 256 blocks (4 m-tiles x full N per block), dbuf LDS weights
    gemmS2_k<4, 2, true><<<dim3(256), 256, 0, stream>>>(y1h, y1l, B2h, B2l, b2, y2h, y2l,
                                                        64, 64, 66, 34);
    // conv3: 256 blocks (1 m-tile x full N per block), dbuf, fused finalize
    gemmS2_k<2, 1, false><<<dim3(256), 256, 0, stream>>>(y2h, y2l, B3h, B3l, b3, y3h, y3l,
                                                         32, 32, 34, 34);
    gemm_k<1, false, 1, 1><<<dim3(64, 3), 256, 0, stream>>>(y3h, y3l, B4h, B4l, part, nullptr, nullptr, nullptr,
                                                            32, 32, 34, 2, 3, 4096, 32, 0);
    fin4_k<<<64, 256, 0, stream>>>(part, b4, zzp, zh, zl);

    // vector quantization (split_cb overlays y1 region — only safe POST-conv)
    split_cb_k<<<256, 256, 0, stream>>>(cb, cbh, cbl, cbn2, cbn_raw, counter);
    vq_mfma_k <<<dim3(16, VQ_NSPLIT), 256, 0, stream>>>(zh, zl, (const uint4*)cbh, (const uint4*)cbl,
                                                        cbn2, pb1, pb2, pcol);
    combine_k <<<16,  256, 0, stream>>>(pb1, pb2, pcol, coarse, flags, list, counter);
    // guard: wave-per-query (32 streams/block), no intra-loop barriers
    guard_k   <<<dim3(256, 8), 256, 0, stream>>>(cb, cbn_raw, zzp, list, counter, gpart);
    // final: wave-per-query parallel reduce over 256 guard partials
    final_k   <<<1024, 256, 0, stream>>>(flags, coarse, gpart, cb, out, out + 4096);
}